// Round 6
// baseline (311.691 us; speedup 1.0000x reference)
//
#include <hip/hip_runtime.h>
#include <stdint.h>

typedef __attribute__((ext_vector_type(8))) _Float16 half8;  // MFMA f16 A/B frag (4 VGPRs)
typedef __attribute__((ext_vector_type(4))) float f32x4;     // MFMA C/D frag

// B=4, C=384, Q=384, H=256, K=256.  w1 is (256 k-rows, 768 h-cols):
//   W_h[k][h]=w1[k][h], W_u[k][h]=w1[k][256+h], W_hu[k][h]=w1[k][512+h]
// pre1[c,q,k] = sum_h (u*h)·W_hu + tu[q,k] + th[c,k] + b1[k]
// out[c,q]    = leaky( sum_k leaky(pre1)·w2[k] + b2 )
// ws: [0, 2359296) fp32 partial sums (4*384*384), atomically accumulated over kt.

__device__ __forceinline__ float leaky(float x) { return fmaxf(x, 0.01f * x); }

template <int CTRL>
__device__ __forceinline__ float dpp_add(float x) {
  int t = __builtin_amdgcn_update_dpp(0, __float_as_int(x), CTRL, 0xF, 0xF, true);
  return x + __int_as_float(t);
}
// sum across the 16 lanes of an aligned 16-lane row (r = lane&15)
__device__ __forceinline__ float row16_sum(float p) {
  p = dpp_add<0xB1>(p);   // quad_perm xor1
  p = dpp_add<0x4E>(p);   // quad_perm xor2
  p = dpp_add<0x124>(p);  // row_ror:4
  p = dpp_add<0x128>(p);  // row_ror:8
  return p;
}

__device__ __forceinline__ half8 cvt8(const float* p) {
  float4 a0 = *(const float4*)p;
  float4 a1 = *(const float4*)(p + 4);
  half8 h;
  h[0] = (_Float16)a0.x; h[1] = (_Float16)a0.y;
  h[2] = (_Float16)a0.z; h[3] = (_Float16)a0.w;
  h[4] = (_Float16)a1.x; h[5] = (_Float16)a1.y;
  h[6] = (_Float16)a1.z; h[7] = (_Float16)a1.w;
  return h;
}

// ---------------- K1: main. Block = 128 q x 64 k (kt-split) x 12 c ------------------
// 4 waves split q (wave w: q-rows w*32..w*32+31). Lane (quad,r): k = kt*64 + 4r + j.
// Register tile: c2=2 x i=2 x j=4 -> 0.375 LDS b128 reads per MFMA.
// VGPR demand ~112 (<128), AGPR 96 (<128): fits 2 waves/SIMD without spill.
// No barriers in the main c-loop; kt-split combined via atomicAdd into `part`.
__global__ void __launch_bounds__(256, 2) k_main(
    const float* __restrict__ hp, const float* __restrict__ up,
    const float* __restrict__ w1, const float* __restrict__ b1,
    const float* __restrict__ w2, float* __restrict__ part) {
  __shared__ __align__(16) _Float16 whuL[64 * 256];   // 32 KB, XOR-swizzled slots
  __shared__ __align__(16) _Float16 hlds[12 * 256];   // 6 KB
  __shared__ __align__(16) float thlds[12 * 64];      // 3 KB (th + b1, this k-slice)

  const int tid = threadIdx.x;
  int t = blockIdx.x;                  // 1536 = kt(4) + 4*(qt(3) + 3*(cc(32) + 32*b(4)))
  const int kt = t & 3;  t >>= 2;
  const int qt = t % 3;  t /= 3;
  const int cc = t & 31;
  const int b = t >> 5;
  const int c0 = cc * 12;

  const int w = tid >> 6, l = tid & 63, quad = l >> 4, r = l & 15;
  const int kbase = kt * 64 + r * 4;   // lane's 4 k = kbase + j

  // ---- stage W_hu k-slice -> LDS (fp32->fp16), swizzled slot = (h>>3)^((krel>>2)&7)
#pragma unroll
  for (int it = 0; it < 8; ++it) {
    int chunk = tid + it * 256;        // 2048 chunks of 8 halfs
    int krel = chunk >> 5;
    int slot = chunk & 31;
    int hsrc = (slot ^ ((krel >> 2) & 7)) * 8;
    half8 v = cvt8(w1 + (kt * 64 + krel) * 768 + 512 + hsrc);
    *(half8*)&whuL[krel * 256 + slot * 8] = v;
  }
  // ---- stage h rows -> LDS fp16 ----
#pragma unroll
  for (int it = 0; it < 3; ++it) {
    int idx = tid + it * 256;          // 768 chunks of 4 halfs
    int c = idx >> 6;
    int hh = (idx & 63) * 4;
    float4 v = *(const float4*)(hp + (b * 384 + c0 + c) * 256 + hh);
    unsigned int lo = (unsigned int)__builtin_bit_cast(unsigned short, (_Float16)v.x) |
                      ((unsigned int)__builtin_bit_cast(unsigned short, (_Float16)v.y) << 16);
    unsigned int hi = (unsigned int)__builtin_bit_cast(unsigned short, (_Float16)v.z) |
                      ((unsigned int)__builtin_bit_cast(unsigned short, (_Float16)v.w) << 16);
    *(uint2*)&hlds[c * 256 + hh] = make_uint2(lo, hi);
  }

  // ---- resident u frags: q = qt*128 + w*32 + i*16 + r ----
  half8 ufr[2][8];
#pragma unroll
  for (int i = 0; i < 2; ++i) {
    const float* urow = up + (b * 384 + qt * 128 + w * 32 + i * 16 + r) * 256 + quad * 8;
#pragma unroll
    for (int s = 0; s < 8; ++s) ufr[i][s] = cvt8(urow + s * 32);
  }

  // ---- tu prologue: tuacc[i][j] = sum_h u·W_u  (B-frags converted from w1/L2) ----
  f32x4 tuacc[2][4];
#pragma unroll
  for (int i = 0; i < 2; ++i)
#pragma unroll
    for (int j = 0; j < 4; ++j) tuacc[i][j] = (f32x4){0.f, 0.f, 0.f, 0.f};
#pragma unroll
  for (int s = 0; s < 8; ++s)
#pragma unroll
    for (int j = 0; j < 4; ++j) {
      half8 wb = cvt8(w1 + (kbase + j) * 768 + 256 + s * 32 + quad * 8);
#pragma unroll
      for (int i = 0; i < 2; ++i)
        tuacc[i][j] = __builtin_amdgcn_mfma_f32_16x16x32_f16(ufr[i][s], wb, tuacc[i][j], 0, 0, 0);
    }

  __syncthreads();   // whuL + hlds ready

  // ---- th prologue: (th + b1) for 12 c-rows x this 64-k slice -> thlds ----
  {
    f32x4 accq[4];
#pragma unroll
    for (int j = 0; j < 4; ++j) accq[j] = (f32x4){0.f, 0.f, 0.f, 0.f};
#pragma unroll
    for (int s = 0; s < 8; ++s) {
      half8 ha = (half8){};
      if (r < 12) ha = *(const half8*)&hlds[r * 256 + s * 32 + quad * 8];
#pragma unroll
      for (int j = 0; j < 4; ++j) {
        half8 wb = cvt8(w1 + (kbase + j) * 768 + s * 32 + quad * 8);
        accq[j] = __builtin_amdgcn_mfma_f32_16x16x32_f16(ha, wb, accq[j], 0, 0, 0);
      }
    }
    f32x4 b1v = *(const f32x4*)(b1 + kbase);
#pragma unroll
    for (int ii = 0; ii < 4; ++ii) {
      int crow = quad * 4 + ii;
      if (crow < 12) {
        f32x4 v = {accq[0][ii] + b1v[0], accq[1][ii] + b1v[1],
                   accq[2][ii] + b1v[2], accq[3][ii] + b1v[3]};
        *(f32x4*)&thlds[crow * 64 + r * 4] = v;
      }
    }
  }
  __syncthreads();   // thlds ready — no more barriers

  f32x4 w2v = *(const f32x4*)(w2 + kbase);
  const int rs = r & 7;          // reader-side slot swizzle

  for (int cp = 0; cp < 6; ++cp) {
    f32x4 acc[2][2][4];
#pragma unroll
    for (int c2 = 0; c2 < 2; ++c2) {
      f32x4 thv = *(const f32x4*)&thlds[(2 * cp + c2) * 64 + r * 4];
#pragma unroll
      for (int i = 0; i < 2; ++i)
#pragma unroll
        for (int j = 0; j < 4; ++j)
          acc[c2][i][j] = tuacc[i][j] + thv[j];
    }

#pragma unroll
    for (int s = 0; s < 8; ++s) {
      half8 bf[4];
#pragma unroll
      for (int j = 0; j < 4; ++j) {
        int krel = r * 4 + j;
        int slot = (s * 4 + quad) ^ rs;
        bf[j] = *(const half8*)&whuL[krel * 256 + slot * 8];
      }
#pragma unroll
      for (int c2 = 0; c2 < 2; ++c2) {
        half8 hc = *(const half8*)&hlds[(2 * cp + c2) * 256 + s * 32 + quad * 8];
#pragma unroll
        for (int i = 0; i < 2; ++i) {
          half8 a = ufr[i][s] * hc;          // 4x v_pk_mul_f16, one live temp
#pragma unroll
          for (int j = 0; j < 4; ++j)
            acc[c2][i][j] =
                __builtin_amdgcn_mfma_f32_16x16x32_f16(a, bf[j], acc[c2][i][j], 0, 0, 0);
        }
      }
    }

    // epilogue: layer-2 partial over this block's 64 k -> atomicAdd into part
#pragma unroll
    for (int c2 = 0; c2 < 2; ++c2) {
      int cg = (b * 384 + c0 + 2 * cp + c2) * 384 + qt * 128 + w * 32;
#pragma unroll
      for (int i = 0; i < 2; ++i)
#pragma unroll
        for (int ii = 0; ii < 4; ++ii) {
          float p = 0.f;
#pragma unroll
          for (int j = 0; j < 4; ++j) {
            float sv = acc[c2][i][j][ii];
            float tt = fmaf(0.495f, fabsf(sv), 0.505f * sv);  // leaky via 0.505x+0.495|x|
            p = fmaf(w2v[j], tt, p);
          }
          p = row16_sum(p);
          if (r == 0) atomicAdd(&part[cg + i * 16 + quad * 4 + ii], p);
        }
    }
  }
}

// ---------------- K2: out = leaky(partial + b2) -------------------------------------
__global__ void k_final(const float* __restrict__ part, const float* __restrict__ b2,
                        float* __restrict__ out) {
  int i = blockIdx.x * 256 + threadIdx.x;        // 589824 exact
  out[i] = leaky(part[i] + b2[0]);
}

extern "C" void kernel_launch(void* const* d_in, const int* in_sizes, int n_in,
                              void* d_out, int out_size, void* d_ws, size_t ws_size,
                              hipStream_t stream) {
  const float* hp = (const float*)d_in[0];   // (4,384,256)
  const float* up = (const float*)d_in[1];   // (4,384,256)
  const float* w1 = (const float*)d_in[2];   // (256,768) — axis-0 is k
  const float* b1 = (const float*)d_in[3];   // (256,)
  const float* w2 = (const float*)d_in[4];   // (1,256)
  const float* b2 = (const float*)d_in[5];   // (1,)
  float* out = (float*)d_out;                // (4,384,384)

  float* part = (float*)d_ws;

  hipMemsetAsync(part, 0, 4 * 384 * 384 * sizeof(float), stream);
  k_main<<<1536, 256, 0, stream>>>(hp, up, w1, b1, w2, part);
  k_final<<<2304, 256, 0, stream>>>(part, b2, out);
}